// Round 14
// baseline (188.296 us; speedup 1.0000x reference)
//
#include <hip/hip_runtime.h>
#include <stdint.h>

#define SOS_IDX 1
#define EOS_IDX 2
#define Bb 32
#define Tt 256
#define Kk 128
#define SK 136          // padded k-stride in ushorts; multiple of 8 (b128 needs 16B align)
#define CSP 16          // chunk span
#define NCc 16          // number of chunks

typedef unsigned short ushort_t;
typedef __attribute__((ext_vector_type(8))) short short8;   // 8 bf16 = 4 VGPR (MFMA A/B)
typedef __attribute__((ext_vector_type(4))) float float4v;  // MFMA C/D

__device__ __forceinline__ ushort_t f2bf(float x) {         // RNE
    union { float f; uint32_t u; } c; c.f = x;
    uint32_t u = c.u + 0x7FFFu + ((c.u >> 16) & 1u);
    return (ushort_t)(u >> 16);
}
__device__ __forceinline__ float bf2f(ushort_t s) {
    union { uint32_t u; float f; } c; c.u = ((uint32_t)s) << 16;
    return c.f;
}
__device__ __forceinline__ float bflo(uint32_t u) {
    union { uint32_t u; float f; } c; c.u = u << 16; return c.f;
}
__device__ __forceinline__ float bfhi(uint32_t u) {
    union { uint32_t u; float f; } c; c.u = u & 0xFFFF0000u; return c.f;
}
__device__ __forceinline__ uint32_t pk2bf(float a, float b) {   // 2x f32 -> bf16x2, RNE
    union { float f; uint32_t u; } ca, cb; ca.f = a; cb.f = b;
    uint32_t ua = ca.u + 0x7FFFu + ((ca.u >> 16) & 1u);
    uint32_t ub = cb.u + 0x7FFFu + ((cb.u >> 16) & 1u);
    return __builtin_amdgcn_perm(ub, ua, 0x07060302u);
}

// ======================= single fused kernel ========================
// Stage A (R13-verified core, W=2 m-split) with prep folded in (afr/ET straight
// from trans), plus a device-scope atomic handoff: after a block's Qt/Ls writes
// + release fence, it bumps cnt[b]; the unique LAST block of batch b (old ==
// 4*NCR-1) acquire-fences and runs the verified stage-B vector chain for that
// batch with its 128 threads. No spin-waits -> no deadlock. Batches with len<=1
// are finalized directly by their masked (st=0,c=0) block.
__global__ __launch_bounds__(128, 2) void crf_fused(const float* __restrict__ h,
                                                    const float* __restrict__ trans,
                                                    const int* __restrict__ y,
                                                    const int* __restrict__ lengths,
                                                    ushort_t* __restrict__ Qt,
                                                    float* __restrict__ Ls,
                                                    unsigned* __restrict__ cnt,
                                                    float* __restrict__ out) {
    const int st = blockIdx.x, b = blockIdx.y, c = blockIdx.z;
    const int tid = threadIdx.x;
    const int lane = tid & 63, w = tid >> 6;             // w in {0,1}
    const int c15 = lane & 15, q = lane >> 4;
    const int len = lengths[b];
    const int NCRb = (len <= 1) ? 0 : ((len + CSP - 1) / CSP);
    int ts = c * CSP; if (ts < 1) ts = 1;
    int te = (c + 1) * CSP; if (te > Tt) te = Tt;
    const int tE = te < len ? te : len;

    __shared__ __align__(16) ushort_t s_S[2][32 * SK];   // stripe dbuf
    __shared__ __align__(16) float    s_eh[CSP][Kk];     // exp(h) per step, f32
    __shared__ float s_wmax[2][2];                       // stageA marks (parity dbuf)
    __shared__ __align__(16) float vbuf[2][Kk];          // stageB vector dbuf
    __shared__ float s_wm[2][2];                         // stageB marks
    __shared__ float red2[2], gred2[2];
    __shared__ unsigned s_last;

    if (ts >= tE) {                                      // masked chunk
        if (st == 0 && c == 0 && tid == 0) {             // len<=1: finalize batch here
            int y0 = y[b * Tt];
            float gold0 = h[(size_t)b * Tt * Kk + y0] + trans[SOS_IDX * Kk + y0];
            float zb = h[(size_t)b * Tt * Kk + EOS_IDX] + trans[SOS_IDX * Kk + EOS_IDX];
            atomicAdd(out, (zb - gold0) * (1.0f / (float)Bb));
        }
        return;
    }
    const int nsteps = tE - ts;
    const size_t qoff = ((size_t)b * NCc + c) * (Kk * Kk);
    const int nbase = st * 32;

    // ---- eh staging (f32, raw exp) ----
    for (int tl = w; tl < nsteps; tl += 2) {
        const float* hr = &h[((size_t)b * Tt + ts + tl) * Kk];
        s_eh[tl][lane]      = __expf(hr[lane]);
        s_eh[tl][lane + 64] = __expf(hr[lane + 64]);
    }

    // ---- A-frags straight from trans (prep folded in): ETT[m][k]=exp(T[k][m]) ----
    short8 afr[4][4];
#pragma unroll
    for (int mt = 0; mt < 4; ++mt)
#pragma unroll
        for (int kt = 0; kt < 4; ++kt) {
            short8 f;
            int m = w * 64 + mt * 16 + c15;
#pragma unroll
            for (int j = 0; j < 8; ++j) {
                int k = kt * 32 + q * 8 + j;
                f[j] = (short)f2bf(__expf(trans[k * Kk + m]));
            }
            afr[mt][kt] = f;
        }
    __syncthreads();                            // eh row 0 ready for init

    // ---- S_1 = M_ts^T directly: s_S[0][nl][k] = exp(T[nbase+nl][k]) * eh0[k] ----
    {
        float lmax = 0.0f;
#pragma unroll
        for (int j = 0; j < 4; ++j) {
            int idx = j * 128 + tid;                     // 512 octets
            int nl = idx >> 4, k8 = (idx & 15) * 8;
            const float* tr = &trans[(nbase + nl) * Kk + k8];
            float4 e0 = *(const float4*)&s_eh[0][k8];
            float4 e1 = *(const float4*)&s_eh[0][k8 + 4];
            float v0 = __expf(tr[0]) * e0.x, v1 = __expf(tr[1]) * e0.y;
            float v2 = __expf(tr[2]) * e0.z, v3 = __expf(tr[3]) * e0.w;
            float v4 = __expf(tr[4]) * e1.x, v5 = __expf(tr[5]) * e1.y;
            float v6 = __expf(tr[6]) * e1.z, v7 = __expf(tr[7]) * e1.w;
            lmax = fmaxf(lmax, fmaxf(fmaxf(fmaxf(v0, v1), fmaxf(v2, v3)),
                                     fmaxf(fmaxf(v4, v5), fmaxf(v6, v7))));
            uint4 o;
            o.x = pk2bf(v0, v1); o.y = pk2bf(v2, v3);
            o.z = pk2bf(v4, v5); o.w = pk2bf(v6, v7);
            *(uint4*)&s_S[0][nl * SK + k8] = o;
        }
#pragma unroll
        for (int o = 1; o < 64; o <<= 1) lmax = fmaxf(lmax, __shfl_xor(lmax, o));
        if (lane == 0) s_wmax[0][w] = lmax;              // valid mark if nsteps==1
    }
    __syncthreads();

    float L = 0.0f;
    int cur = 0;
    for (int s = 1; s < nsteps; ++s) {
        float invG = 1.0f;
        if ((s & 3) == 0) {                              // apply (mark from s-1)
            int ms = ((s >> 2) - 1) & 1;
            float g = fmaxf(s_wmax[ms][0], s_wmax[ms][1]);
            invG = 1.0f / g;
            L += __logf(g);
        }
        const bool isMark = ((s & 3) == 3) || (s == nsteps - 1);

        float sc[4][4];                                  // eh[m]*invG for my 16 rows
#pragma unroll
        for (int mt = 0; mt < 4; ++mt) {
            float4 e = *(const float4*)&s_eh[s][w * 64 + mt * 16 + q * 4];
            sc[mt][0] = e.x * invG; sc[mt][1] = e.y * invG;
            sc[mt][2] = e.z * invG; sc[mt][3] = e.w * invG;
        }

        short8 bfr[2][4];                                // stripe B-frags (verified)
        const ushort_t* ps = s_S[cur];
#pragma unroll
        for (int nt = 0; nt < 2; ++nt)
#pragma unroll
            for (int kt = 0; kt < 4; ++kt)
                bfr[nt][kt] = *(const short8*)&ps[(nt * 16 + c15) * SK + kt * 32 + q * 8];

        float4v acc[4][2];
#pragma unroll
        for (int mt = 0; mt < 4; ++mt)
#pragma unroll
            for (int nt = 0; nt < 2; ++nt) acc[mt][nt] = (float4v){0.f, 0.f, 0.f, 0.f};
#pragma unroll
        for (int kt = 0; kt < 4; ++kt)
#pragma unroll
            for (int mt = 0; mt < 4; ++mt)
#pragma unroll
                for (int nt = 0; nt < 2; ++nt)
                    acc[mt][nt] = __builtin_amdgcn_mfma_f32_16x16x32_bf16(
                        afr[mt][kt], bfr[nt][kt], acc[mt][nt], 0, 0, 0);

        // epilogue (verified addressing; lmax only on marks)
        int nxt = cur ^ 1;
        ushort_t* pn = s_S[nxt];
        float lmax = 0.0f;
#pragma unroll
        for (int mt = 0; mt < 4; ++mt)
#pragma unroll
            for (int nt = 0; nt < 2; ++nt) {
                float v0 = acc[mt][nt][0] * sc[mt][0];
                float v1 = acc[mt][nt][1] * sc[mt][1];
                float v2 = acc[mt][nt][2] * sc[mt][2];
                float v3 = acc[mt][nt][3] * sc[mt][3];
                if (isMark)
                    lmax = fmaxf(lmax, fmaxf(fmaxf(v0, v1), fmaxf(v2, v3)));
                uint2 u; u.x = pk2bf(v0, v1); u.y = pk2bf(v2, v3);
                *(uint2*)&pn[(nt * 16 + c15) * SK + w * 64 + mt * 16 + q * 4] = u;
            }
        if (isMark) {
#pragma unroll
            for (int o = 1; o < 64; o <<= 1) lmax = fmaxf(lmax, __shfl_xor(lmax, o));
            if (lane == 0) s_wmax[(s >> 2) & 1][w] = lmax;
        }
        __syncthreads();
        cur = nxt;
    }

    // ---- dump (verified orientation): Qt[n][nbase+kl] = s_S[kl][n] ----
    int fs = ((nsteps - 1) >> 2) & 1;
    float Gf = fmaxf(s_wmax[fs][0], s_wmax[fs][1]);
    float dsc = 1.0f / Gf;
    L += __logf(Gf);
    const ushort_t* pc = s_S[cur];
#pragma unroll
    for (int j = 0; j < 4; ++j) {
        int idx = j * 128 + tid;
        int n = idx & 127, o = idx >> 7;
        uint4 gv; ushort_t* gp = (ushort_t*)&gv;
#pragma unroll
        for (int r = 0; r < 8; ++r)
            gp[r] = f2bf(bf2f(pc[(o * 8 + r) * SK + n]) * dsc);
        *(uint4*)&Qt[qoff + (size_t)n * Kk + nbase + o * 8] = gv;
    }
    if (tid == 0) Ls[(((size_t)b * NCc + c) << 2) + st] = L;

    // ---- handoff: last block of batch b runs the stage-B chain ----
    __threadfence();                                     // release my Qt/Ls writes
    __syncthreads();                                     // all threads' fences done
    if (tid == 0) {
        unsigned old = atomicAdd(&cnt[b], 1u);
        s_last = (old == (unsigned)(4 * NCRb) - 1u) ? 1u : 0u;
    }
    __syncthreads();
    if (!s_last) return;
    __threadfence();                                     // acquire others' writes

    // ======== stage B (verified math, 128-thread variant) ========
    // gold: t = tid and t = tid+128
    {
        float g = 0.0f;
        if (tid < len) {
            int yt   = y[b * Tt + tid];
            int prev = (tid == 0) ? SOS_IDX : y[b * Tt + tid - 1];
            g = h[((size_t)b * Tt + tid) * Kk + yt] + trans[prev * Kk + yt];
        }
        int t1 = tid + 128;
        if (t1 < len) {
            int yt   = y[b * Tt + t1];
            int prev = y[b * Tt + t1 - 1];
            g += h[((size_t)b * Tt + t1) * Kk + yt] + trans[prev * Kk + yt];
        }
#pragma unroll
        for (int off = 32; off > 0; off >>= 1) g += __shfl_down(g, off);
        if (lane == 0) gred2[w] = g;
    }

    // init v0 = exp(alpha0 - m0); state n = tid
    float a0 = h[((size_t)b * Tt) * Kk + tid] + trans[SOS_IDX * Kk + tid];
    float m0 = a0;
#pragma unroll
    for (int o = 1; o < 64; o <<= 1) m0 = fmaxf(m0, __shfl_xor(m0, o));
    if (lane == 0) red2[w] = m0;
    __syncthreads();
    m0 = fmaxf(red2[0], red2[1]);
    float cacc = m0;
    vbuf[0][tid] = __expf(a0 - m0);
    __syncthreads();

    const size_t lbase = (size_t)b * NCc;
    int cb = 0;
    for (int ci = 0; ci < NCRb; ++ci) {
        float4 Ls4 = *(const float4*)&Ls[(lbase + ci) << 2];
        float Lref = fmaxf(fmaxf(Ls4.x, Ls4.y), fmaxf(Ls4.z, Ls4.w));
        float e0 = __expf(Ls4.x - Lref), e1 = __expf(Ls4.y - Lref);
        float e2 = __expf(Ls4.z - Lref), e3 = __expf(Ls4.w - Lref);
        float invG = 1.0f;
        if (ci > 0 && (ci & 3) == 0) {                   // apply (verified cadence)
            int ms = ((ci >> 2) - 1) & 1;
            float gg = fmaxf(s_wm[ms][0], s_wm[ms][1]);
            invG = 1.0f / gg;
            cacc += __logf(gg);
        }
        cacc += Lref;

        const uint4* qp = (const uint4*)(Qt + (lbase + ci) * (Kk * Kk) + (size_t)tid * Kk);
        float p0 = 0.f, p1 = 0.f, p2 = 0.f, p3 = 0.f;    // per-stripe partials
#pragma unroll
        for (int r = 0; r < 16; ++r) {
            uint4 d = qp[r];
            float4 v0 = *(const float4*)&vbuf[cb][r * 8];
            float4 v1 = *(const float4*)&vbuf[cb][r * 8 + 4];
            float* pp = (r < 4) ? &p0 : (r < 8) ? &p1 : (r < 12) ? &p2 : &p3;
            float a = *pp;
            a = fmaf(bflo(d.x), v0.x, a);
            a = fmaf(bfhi(d.x), v0.y, a);
            a = fmaf(bflo(d.y), v0.z, a);
            a = fmaf(bfhi(d.y), v0.w, a);
            a = fmaf(bflo(d.z), v1.x, a);
            a = fmaf(bfhi(d.z), v1.y, a);
            a = fmaf(bflo(d.w), v1.z, a);
            a = fmaf(bfhi(d.w), v1.w, a);
            *pp = a;
        }
        float s = (fmaf(e0, p0, e1 * p1) + fmaf(e2, p2, e3 * p3)) * invG;

        const bool isMark = ((ci & 3) == 3) || (ci == NCRb - 1);
        if (isMark) {
            float wm = s;
#pragma unroll
            for (int o = 1; o < 64; o <<= 1) wm = fmaxf(wm, __shfl_xor(wm, o));
            if (lane == 0) s_wm[(ci >> 2) & 1][w] = wm;
        }
        int nxt = cb ^ 1;
        vbuf[nxt][tid] = s;
        __syncthreads();
        cb = nxt;
    }

    if (tid == 0) {
        float zb = cacc + __logf(vbuf[cb][EOS_IDX]);
        atomicAdd(out, (zb - (gred2[0] + gred2[1])) * (1.0f / (float)Bb));
    }
}

extern "C" void kernel_launch(void* const* d_in, const int* in_sizes, int n_in,
                              void* d_out, int out_size, void* d_ws, size_t ws_size,
                              hipStream_t stream) {
    const float* h       = (const float*)d_in[0];
    const float* trans   = (const float*)d_in[1];
    const int*   y       = (const int*)d_in[2];
    const int*   lengths = (const int*)d_in[3];
    // d_in[4] = mask: derived from lengths instead.
    float* out = (float*)d_out;

    ushort_t* Qt  = (ushort_t*)d_ws;                        // 16.8 MB
    float*    Ls  = (float*)(Qt + (size_t)Bb * NCc * Kk * Kk);  // 8 KB
    unsigned* cnt = (unsigned*)(Ls + (size_t)Bb * NCc * 4);     // 128 B

    hipMemsetAsync(out, 0, sizeof(float), stream);
    hipMemsetAsync(Ls, 0, (size_t)Bb * NCc * 4 * sizeof(float) + Bb * sizeof(unsigned), stream);
    crf_fused<<<dim3(4, Bb, NCc), 128, 0, stream>>>(h, trans, y, lengths, Qt, Ls, cnt, out);
}

// Round 15
// 111.890 us; speedup vs baseline: 1.6829x; 1.6829x over previous
//
#include <hip/hip_runtime.h>
#include <stdint.h>

#define SOS_IDX 1
#define EOS_IDX 2
#define Bb 32
#define Tt 256
#define Kk 128
#define SK 136          // padded k-stride in ushorts; multiple of 8 (b128 needs 16B align)
#define CSP 16          // chunk span (NC = 16)
#define NCc 16

typedef unsigned short ushort_t;
typedef __attribute__((ext_vector_type(8))) short short8;   // 8 bf16 = 4 VGPR (MFMA A/B)
typedef __attribute__((ext_vector_type(4))) float float4v;  // MFMA C/D

__device__ __forceinline__ ushort_t f2bf(float x) {         // RNE
    union { float f; uint32_t u; } c; c.f = x;
    uint32_t u = c.u + 0x7FFFu + ((c.u >> 16) & 1u);
    return (ushort_t)(u >> 16);
}
__device__ __forceinline__ float bf2f(ushort_t s) {
    union { uint32_t u; float f; } c; c.u = ((uint32_t)s) << 16;
    return c.f;
}
__device__ __forceinline__ float bflo(uint32_t u) {
    union { uint32_t u; float f; } c; c.u = u << 16; return c.f;
}
__device__ __forceinline__ float bfhi(uint32_t u) {
    union { uint32_t u; float f; } c; c.u = u & 0xFFFF0000u; return c.f;
}
__device__ __forceinline__ uint32_t pk2bf(float a, float b) {   // 2x f32 -> bf16x2, RNE
    union { float f; uint32_t u; } ca, cb; ca.f = a; cb.f = b;
    uint32_t ua = ca.u + 0x7FFFu + ((ca.u >> 16) & 1u);
    uint32_t ub = cb.u + 0x7FFFu + ((cb.u >> 16) & 1u);
    return __builtin_amdgcn_perm(ub, ua, 0x07060302u);
}

// ---------------- prep: ETT/ET tables + per-batch gold score + out zeroing ---------
// R14 postmortem: folding prep INTO stage A spilled the afr hoist (VGPR 84) and
// un-coalesced the trans reads (FETCH 1.2->7.3MB) -> 133us. Keep prep separate
// (R12/R13-verified), but absorb the gold kernel-work and the out-memset here:
// blocks 0-15 build ETT/ET (coalesced); blocks 16-47 compute gsum[b]; block 0
// zeroes out (safe: prep precedes stage B in stream order).
__global__ __launch_bounds__(256) void crf_prep(const float* __restrict__ trans,
                                                const float* __restrict__ h,
                                                const int* __restrict__ y,
                                                const int* __restrict__ lengths,
                                                ushort_t* __restrict__ ETT,
                                                ushort_t* __restrict__ ET,
                                                float* __restrict__ gsum,
                                                float* __restrict__ out) {
    const int tid = threadIdx.x, bid = blockIdx.x;
    if (bid < 16) {
        if (bid == 0 && tid == 0) out[0] = 0.0f;
        int idx = ((bid & 7) * 256 + tid) * 8;
        if (bid < 8) {                                  // ETT (transposed reads)
            int m = idx >> 7, k0 = idx & 127;
            float e[8];
#pragma unroll
            for (int r = 0; r < 8; ++r) e[r] = __expf(trans[(k0 + r) * Kk + m]);
            uint4 o;
            o.x = pk2bf(e[0], e[1]); o.y = pk2bf(e[2], e[3]);
            o.z = pk2bf(e[4], e[5]); o.w = pk2bf(e[6], e[7]);
            *(uint4*)&ETT[idx] = o;
        } else {                                        // ET (coalesced)
            float4 a = *(const float4*)&trans[idx];
            float4 b = *(const float4*)&trans[idx + 4];
            uint4 o;
            o.x = pk2bf(__expf(a.x), __expf(a.y));
            o.y = pk2bf(__expf(a.z), __expf(a.w));
            o.z = pk2bf(__expf(b.x), __expf(b.y));
            o.w = pk2bf(__expf(b.z), __expf(b.w));
            *(uint4*)&ET[idx] = o;
        }
        return;
    }
    // ---- gold score for batch b = bid - 16 ----
    const int b = bid - 16;
    const int len = lengths[b];
    float g = 0.0f;
    if (tid < len) {
        int yt   = y[b * Tt + tid];
        int prev = (tid == 0) ? SOS_IDX : y[b * Tt + tid - 1];
        g = h[((size_t)b * Tt + tid) * Kk + yt] + trans[prev * Kk + yt];
    }
#pragma unroll
    for (int off = 32; off > 0; off >>= 1) g += __shfl_down(g, off);
    __shared__ float ws[4];
    if ((tid & 63) == 0) ws[tid >> 6] = g;
    __syncthreads();
    if (tid == 0) gsum[b] = ws[0] + ws[1] + ws[2] + ws[3];
}

// ---------------- stage A: 128-thread blocks, 2-way m-split (R13-verified) ----------
__global__ __launch_bounds__(128, 2) void crf_stageA(const float* __restrict__ h,
                                                     const ushort_t* __restrict__ ETT,
                                                     const ushort_t* __restrict__ ET,
                                                     const int* __restrict__ lengths,
                                                     ushort_t* __restrict__ Qt,
                                                     float* __restrict__ Ls,
                                                     int NC) {
    const int st = blockIdx.x, b = blockIdx.y, c = blockIdx.z;
    const int tid = threadIdx.x;
    const int lane = tid & 63, w = tid >> 6;             // w in {0,1}
    const int c15 = lane & 15, q = lane >> 4;
    const int len = lengths[b];
    int ts = c * CSP; if (ts < 1) ts = 1;
    int te = (c + 1) * CSP; if (te > Tt) te = Tt;
    const int tE = te < len ? te : len;
    if (ts >= tE) return;                       // masked chunk: no work, no writes
    const int nsteps = tE - ts;
    const size_t qoff = ((size_t)b * NC + c) * (Kk * Kk);
    const int nbase = st * 32;

    __shared__ __align__(16) ushort_t s_S[2][32 * SK];   // stripe dbuf
    __shared__ __align__(16) float    s_eh[CSP][Kk];     // exp(h) per step, f32
    __shared__ float s_wmax[2][2];                       // dbuf by mark parity, 2 waves

    // ---- eh staging (f32, raw exp, no max-subtract) ----
    for (int tl = w; tl < nsteps; tl += 2) {
        const float* hr = &h[((size_t)b * Tt + ts + tl) * Kk];
        s_eh[tl][lane]      = __expf(hr[lane]);
        s_eh[tl][lane + 64] = __expf(hr[lane + 64]);
    }

    // ---- A-frags from global ETT (16B loads, L2-hot; 64 VGPRs) ----
    short8 afr[4][4];
#pragma unroll
    for (int mt = 0; mt < 4; ++mt)
#pragma unroll
        for (int kt = 0; kt < 4; ++kt)
            afr[mt][kt] = *(const short8*)&ETT[(w * 64 + mt * 16 + c15) * Kk + kt * 32 + q * 8];
    __syncthreads();                            // eh row 0 ready for init

    // ---- S_1 = M_ts^T directly: s_S[0][nl][k] = ET[nbase+nl][k] * eh0[k] ----
    {
        float lmax = 0.0f;
#pragma unroll
        for (int j = 0; j < 4; ++j) {
            int idx = j * 128 + tid;                     // 512 octets
            int nl = idx >> 4, k8 = (idx & 15) * 8;
            uint4 ev = *(const uint4*)&ET[(nbase + nl) * Kk + k8];
            float4 e0 = *(const float4*)&s_eh[0][k8];
            float4 e1 = *(const float4*)&s_eh[0][k8 + 4];
            float v0 = bflo(ev.x) * e0.x, v1 = bfhi(ev.x) * e0.y;
            float v2 = bflo(ev.y) * e0.z, v3 = bfhi(ev.y) * e0.w;
            float v4 = bflo(ev.z) * e1.x, v5 = bfhi(ev.z) * e1.y;
            float v6 = bflo(ev.w) * e1.z, v7 = bfhi(ev.w) * e1.w;
            lmax = fmaxf(lmax, fmaxf(fmaxf(fmaxf(v0, v1), fmaxf(v2, v3)),
                                     fmaxf(fmaxf(v4, v5), fmaxf(v6, v7))));
            uint4 o;
            o.x = pk2bf(v0, v1); o.y = pk2bf(v2, v3);
            o.z = pk2bf(v4, v5); o.w = pk2bf(v6, v7);
            *(uint4*)&s_S[0][nl * SK + k8] = o;
        }
#pragma unroll
        for (int o = 1; o < 64; o <<= 1) lmax = fmaxf(lmax, __shfl_xor(lmax, o));
        if (lane == 0) s_wmax[0][w] = lmax;              // valid mark if nsteps==1
    }
    __syncthreads();

    float L = 0.0f;
    int cur = 0;
    for (int s = 1; s < nsteps; ++s) {
        float invG = 1.0f;
        if ((s & 3) == 0) {                              // apply (mark from s-1)
            int ms = ((s >> 2) - 1) & 1;
            float g = fmaxf(s_wmax[ms][0], s_wmax[ms][1]);
            invG = 1.0f / g;
            L += __logf(g);
        }
        const bool isMark = ((s & 3) == 3) || (s == nsteps - 1);

        float sc[4][4];                                  // eh[m]*invG for my 16 rows
#pragma unroll
        for (int mt = 0; mt < 4; ++mt) {
            float4 e = *(const float4*)&s_eh[s][w * 64 + mt * 16 + q * 4];
            sc[mt][0] = e.x * invG; sc[mt][1] = e.y * invG;
            sc[mt][2] = e.z * invG; sc[mt][3] = e.w * invG;
        }

        short8 bfr[2][4];                                // stripe B-frags (verified)
        const ushort_t* ps = s_S[cur];
#pragma unroll
        for (int nt = 0; nt < 2; ++nt)
#pragma unroll
            for (int kt = 0; kt < 4; ++kt)
                bfr[nt][kt] = *(const short8*)&ps[(nt * 16 + c15) * SK + kt * 32 + q * 8];

        float4v acc[4][2];
#pragma unroll
        for (int mt = 0; mt < 4; ++mt)
#pragma unroll
            for (int nt = 0; nt < 2; ++nt) acc[mt][nt] = (float4v){0.f, 0.f, 0.f, 0.f};
#pragma unroll
        for (int kt = 0; kt < 4; ++kt)
#pragma unroll
            for (int mt = 0; mt < 4; ++mt)
#pragma unroll
                for (int nt = 0; nt < 2; ++nt)
                    acc[mt][nt] = __builtin_amdgcn_mfma_f32_16x16x32_bf16(
                        afr[mt][kt], bfr[nt][kt], acc[mt][nt], 0, 0, 0);

        // epilogue (verified addressing; lmax only on marks)
        int nxt = cur ^ 1;
        ushort_t* pn = s_S[nxt];
        float lmax = 0.0f;
#pragma unroll
        for (int mt = 0; mt < 4; ++mt)
#pragma unroll
            for (int nt = 0; nt < 2; ++nt) {
                float v0 = acc[mt][nt][0] * sc[mt][0];
                float v1 = acc[mt][nt][1] * sc[mt][1];
                float v2 = acc[mt][nt][2] * sc[mt][2];
                float v3 = acc[mt][nt][3] * sc[mt][3];
                if (isMark)
                    lmax = fmaxf(lmax, fmaxf(fmaxf(v0, v1), fmaxf(v2, v3)));
                uint2 u; u.x = pk2bf(v0, v1); u.y = pk2bf(v2, v3);
                *(uint2*)&pn[(nt * 16 + c15) * SK + w * 64 + mt * 16 + q * 4] = u;
            }
        if (isMark) {
#pragma unroll
            for (int o = 1; o < 64; o <<= 1) lmax = fmaxf(lmax, __shfl_xor(lmax, o));
            if (lane == 0) s_wmax[(s >> 2) & 1][w] = lmax;
        }
        __syncthreads();
        cur = nxt;
    }

    // dump (verified orientation): Qt[n][nbase+kl] = s_S[kl][n]
    int fs = ((nsteps - 1) >> 2) & 1;
    float Gf = fmaxf(s_wmax[fs][0], s_wmax[fs][1]);
    float dsc = 1.0f / Gf;
    L += __logf(Gf);
    const ushort_t* pc = s_S[cur];
#pragma unroll
    for (int j = 0; j < 4; ++j) {
        int idx = j * 128 + tid;
        int n = idx & 127, o = idx >> 7;
        uint4 gv; ushort_t* gp = (ushort_t*)&gv;
#pragma unroll
        for (int r = 0; r < 8; ++r)
            gp[r] = f2bf(bf2f(pc[(o * 8 + r) * SK + n]) * dsc);
        *(uint4*)&Qt[qoff + (size_t)n * Kk + nbase + o * 8] = gv;
    }
    if (tid == 0) Ls[(((size_t)b * NC + c) << 2) + st] = L;
}

// ---------------- stage B: 512-thread vector chain (R13-verified, gold via gsum) ----
__global__ __launch_bounds__(512, 1) void crf_stageB(const float* __restrict__ h,
                                                     const float* __restrict__ trans,
                                                     const int* __restrict__ lengths,
                                                     const ushort_t* __restrict__ Qt,
                                                     const float* __restrict__ Ls,
                                                     const float* __restrict__ gsum,
                                                     float* __restrict__ out,
                                                     int NC) {
    const int b = blockIdx.x;
    const int tid = threadIdx.x;
    const int lane = tid & 63, w = tid >> 6;
    const int n = tid >> 2, qr = tid & 3;
    const int len = lengths[b];

    __shared__ __align__(16) float vbuf[2][Kk];
    __shared__ float s_wmax[2][8];
    __shared__ float red[8];

    // ---- init v0 = exp(alpha0 - m0) ----
    float a0 = h[((size_t)b * Tt) * Kk + n] + trans[SOS_IDX * Kk + n];
    float m0 = a0;
#pragma unroll
    for (int o = 1; o < 64; o <<= 1) m0 = fmaxf(m0, __shfl_xor(m0, o));
    if (lane == 0) red[w] = m0;
    __syncthreads();
    {
        float4 r0 = *(const float4*)&red[0];
        float4 r1 = *(const float4*)&red[4];
        m0 = fmaxf(fmaxf(fmaxf(r0.x, r0.y), fmaxf(r0.z, r0.w)),
                   fmaxf(fmaxf(r1.x, r1.y), fmaxf(r1.z, r1.w)));
    }
    float cacc = m0;
    if (qr == 0) vbuf[0][n] = __expf(a0 - m0);

    const int NCR = (len <= 1) ? 0 : min(NC, (len + CSP - 1) / CSP);
    const size_t lbase = (size_t)b * NC;
    uint4 qb[4];
    if (NCR > 0) {
        const uint4* qp = (const uint4*)(Qt + lbase * (Kk * Kk) + n * Kk + qr * 32);
#pragma unroll
        for (int r = 0; r < 4; ++r) qb[r] = qp[r];
    }
    __syncthreads();

    int cur = 0;
    for (int ci = 0; ci < NCR; ++ci) {
        uint4 qn[4];
        if (ci + 1 < NCR) {
            const uint4* qp2 = (const uint4*)(Qt + (lbase + ci + 1) * (Kk * Kk) + n * Kk + qr * 32);
#pragma unroll
            for (int r = 0; r < 4; ++r) qn[r] = qp2[r];
        }
        float4 Ls4 = *(const float4*)&Ls[(lbase + ci) << 2];
        float Lref = fmaxf(fmaxf(Ls4.x, Ls4.y), fmaxf(Ls4.z, Ls4.w));
        float lsq = (qr == 0) ? Ls4.x : (qr == 1) ? Ls4.y : (qr == 2) ? Ls4.z : Ls4.w;
        float eQ = __expf(lsq - Lref);
        float invG = 1.0f;
        if (ci > 0 && (ci & 3) == 0) {                   // apply
            int ms = ((ci >> 2) - 1) & 1;
            float4 r0 = *(const float4*)&s_wmax[ms][0];
            float4 r1 = *(const float4*)&s_wmax[ms][4];
            float g = fmaxf(fmaxf(fmaxf(r0.x, r0.y), fmaxf(r0.z, r0.w)),
                            fmaxf(fmaxf(r1.x, r1.y), fmaxf(r1.z, r1.w)));
            invG = 1.0f / g;
            cacc += __logf(g);
        }
        cacc += Lref;

        float acc0 = 0.0f, acc1 = 0.0f;
#pragma unroll
        for (int r = 0; r < 4; ++r) {
            uint4 d = qb[r];
            float4 v0 = *(const float4*)&vbuf[cur][qr * 32 + r * 8];
            float4 v1 = *(const float4*)&vbuf[cur][qr * 32 + r * 8 + 4];
            acc0 = fmaf(bflo(d.x), v0.x, acc0);
            acc1 = fmaf(bfhi(d.x), v0.y, acc1);
            acc0 = fmaf(bflo(d.y), v0.z, acc0);
            acc1 = fmaf(bfhi(d.y), v0.w, acc1);
            acc0 = fmaf(bflo(d.z), v1.x, acc0);
            acc1 = fmaf(bfhi(d.z), v1.y, acc1);
            acc0 = fmaf(bflo(d.w), v1.z, acc0);
            acc1 = fmaf(bfhi(d.w), v1.w, acc1);
        }
        float s = (acc0 + acc1) * (eQ * invG);
        s += __shfl_xor(s, 1);                           // combine 4 quarters
        s += __shfl_xor(s, 2);

        const bool isMark = ((ci & 3) == 3) || (ci == NCR - 1);
        if (isMark) {
            float wm = s;
#pragma unroll
            for (int o = 1; o < 64; o <<= 1) wm = fmaxf(wm, __shfl_xor(wm, o));
            if (lane == 0) s_wmax[(ci >> 2) & 1][w] = wm;
        }
        int nxt = cur ^ 1;
        if (qr == 0) vbuf[nxt][n] = s;
        __syncthreads();
        cur = nxt;
        if (ci + 1 < NCR) {
#pragma unroll
            for (int r = 0; r < 4; ++r) qb[r] = qn[r];
        }
    }

    if (tid == 0) {
        float zb = cacc + __logf(vbuf[cur][EOS_IDX]);
        atomicAdd(out, (zb - gsum[b]) * (1.0f / (float)Bb));
    }
}

extern "C" void kernel_launch(void* const* d_in, const int* in_sizes, int n_in,
                              void* d_out, int out_size, void* d_ws, size_t ws_size,
                              hipStream_t stream) {
    const float* h       = (const float*)d_in[0];
    const float* trans   = (const float*)d_in[1];
    const int*   y       = (const int*)d_in[2];
    const int*   lengths = (const int*)d_in[3];
    // d_in[4] = mask: derived from lengths instead.
    float* out = (float*)d_out;

    ushort_t* Qt   = (ushort_t*)d_ws;                       // 16.8 MB
    ushort_t* ETT  = Qt + (size_t)Bb * NCc * Kk * Kk;       // 32 KB
    ushort_t* ET   = ETT + Kk * Kk;                         // 32 KB
    float*    Ls   = (float*)(ET + Kk * Kk);                // 8 KB
    float*    gsum = Ls + (size_t)Bb * NCc * 4;             // 128 B

    crf_prep<<<48, 256, 0, stream>>>(trans, h, y, lengths, ETT, ET, gsum, out);
    crf_stageA<<<dim3(4, Bb, NCc), 128, 0, stream>>>(h, ETT, ET, lengths, Qt, Ls, NCc);
    crf_stageB<<<Bb, 512, 0, stream>>>(h, trans, lengths, Qt, Ls, gsum, out, NCc);
}